// Round 17
// baseline (75.457 us; speedup 1.0000x reference)
//
#include <hip/hip_runtime.h>
#include <hip/hip_bf16.h>
#include <hip/hip_fp16.h>
#include <cstdint>
#include <cstddef>

typedef __attribute__((ext_vector_type(8))) short bf16x8;
typedef __attribute__((ext_vector_type(8))) _Float16 f16x8;
typedef __attribute__((ext_vector_type(4))) float f32x4;
typedef __attribute__((ext_vector_type(4))) unsigned u32x4;

__device__ inline unsigned short f2bf(float f) {   // RNE bf16
    __hip_bfloat16 h = __float2bfloat16(f);
    return __builtin_bit_cast(unsigned short, h);
}
__device__ inline unsigned short f2h(float f) {    // RNE fp16
    _Float16 h = (_Float16)f;
    return __builtin_bit_cast(unsigned short, h);
}
__device__ inline unsigned cvtpkrtz(float lo, float hi) {  // 2xf32 -> packed fp16
    unsigned pk;
    asm("v_cvt_pkrtz_f16_f32 %0, %1, %2" : "=v"(pk) : "v"(lo), "v"(hi));
    return pk;
}

// ---------------------------------------------------------------------------
// One-shot prep.
// Blocks 0..286: P[t,h] (trig table in LDS).
// Blocks 287..756: weight fragments (id carve, 120320 ids).
// Block 757: O(N) counting sort of edges by key se*8|(re&7) (R13-proven).
// wc2f2 (fp16): 2 k-halves x 5 ks x 512 (ks=4 zero-padded tail):
//   frag[(h*5+ks)*512+l*8+j] = Wc2[h*144+ks*32+(l>>4)*8+j][l&15] or 0.
// ---------------------------------------------------------------------------
__global__ void prep_kernel(
    const float* __restrict__ W_emb, const float* __restrict__ b_emb,
    const float* __restrict__ Ws1, const float* __restrict__ bs1,
    const float* __restrict__ Wr1, const float* __restrict__ br1,
    const float* __restrict__ Ws2, const float* __restrict__ bs2,
    const float* __restrict__ Wr2, const float* __restrict__ br2,
    const float* __restrict__ Wc1, const float* __restrict__ bc1,
    const float* __restrict__ Wc2,
    const int* __restrict__ se, const int* __restrict__ re,
    float* __restrict__ P, float* __restrict__ bias1, float* __restrict__ bias2,
    unsigned short* __restrict__ wg1f, unsigned short* __restrict__ wg2f,
    unsigned short* __restrict__ wg3fT, unsigned short* __restrict__ wc2f2,
    int* __restrict__ eidx, int* __restrict__ sidx, int* __restrict__ ridx)
{
    const int tid = threadIdx.x;

    if (blockIdx.x < 287) {            // ---- P section (ids 0..73439) ----
        __shared__ float sv[3][16], cv[3][16];
        const int base = blockIdx.x * 256;
        const int t0 = base / 288;
        if (tid < 48) {
            const int dt = tid >> 4, i = tid & 15;
            const int ii = i >> 1;
            const float div = expf(-1.1512925464970229f * (float)ii);
            const float ang = (float)(t0 + dt) * div;
            sv[dt][i] = sinf(ang);
            cv[dt][i] = cosf(ang);
        }
        __syncthreads();
        const int id = base + tid;
        if (id < 73440) {
            const int t = id / 288, ho = id % 288;
            const int dt = t - t0;
            float acc = bc1[ho];
#pragma unroll
            for (int i = 0; i < 8; i++) {
                acc += sv[dt + 1][2 * i] * Wc1[(size_t)(128 + 2 * i) * 288 + ho];
                acc += cv[dt + 1][2 * i] * Wc1[(size_t)(129 + 2 * i) * 288 + ho];
                acc += sv[dt][2 * i]     * Wc1[(size_t)(272 + 2 * i) * 288 + ho];
                acc += cv[dt][2 * i]     * Wc1[(size_t)(273 + 2 * i) * 288 + ho];
            }
            P[id] = acc;
        }
        return;
    }

    if (blockIdx.x == 757) {           // ---- O(N) edge counting sort ----
        __shared__ int sse[1024], sre[1024];
        __shared__ int hist[1024];
        __shared__ int scn[256];
        for (int i = tid; i < 1024; i += 256) {
            sse[i] = se[i]; sre[i] = re[i]; hist[i] = 0;
        }
        __syncthreads();
        for (int i = tid; i < 1024; i += 256)
            atomicAdd(&hist[sse[i] * 8 + (sre[i] & 7)], 1);
        __syncthreads();
        int loc[4]; int s = 0;
#pragma unroll
        for (int j = 0; j < 4; j++) { loc[j] = s; s += hist[tid * 4 + j]; }
        scn[tid] = s;
        __syncthreads();
        for (int off = 1; off < 256; off <<= 1) {
            const int v = (tid >= off) ? scn[tid - off] : 0;
            __syncthreads();
            scn[tid] += v;
            __syncthreads();
        }
        const int excl = scn[tid] - s;
#pragma unroll
        for (int j = 0; j < 4; j++) hist[tid * 4 + j] = excl + loc[j];
        __syncthreads();
        for (int i = tid; i < 1024; i += 256) {
            const int key = sse[i] * 8 + (sre[i] & 7);
            const int slot = atomicAdd(&hist[key], 1);
            eidx[slot] = i; sidx[slot] = sse[i]; ridx[slot] = sre[i];
        }
        return;
    }

    int id = (blockIdx.x - 287) * 256 + tid;

    if (id < 8192) {    // wg1f: [W_emb@Ws1 | W_emb@Wr1], K padded 16->32
        const int y = id >> 12, r = id & 4095;
        const int f = r >> 9, l = (r >> 3) & 63, j = r & 7;
        const int k = ((l >> 4) << 3) + j;          // 0..31
        const int n = f * 16 + (l & 15);
        float v = 0.f;
        if (k < 16) {
            const float* Wx = y ? Wr1 : Ws1;
            for (int d = 0; d < 128; d++) v += W_emb[k * 128 + d] * Wx[d * 128 + n];
        }
        wg1f[id] = f2bf(v);
        return;
    }
    id -= 8192;

    if (id < 256) {     // bias1 = [bs1 + b_emb@Ws1 | br1 + b_emb@Wr1]
        const int y = id >> 7, c = id & 127;
        const float* Wx = y ? Wr1 : Ws1;
        float v = (y ? br1 : bs1)[c];
        for (int d = 0; d < 128; d++) v += b_emb[d] * Wx[d * 128 + c];
        bias1[id] = v;
        return;
    }
    id -= 256;

    if (id < 32768) {   // wg2f: [Ws2 | Wr2] fragments
        const int y = id >> 14, r = id & 16383;
        const int f = r >> 9, l = (r >> 3) & 63, j = r & 7;
        const int ks = f >> 3, nf = f & 7;
        const int k = ks * 32 + ((l >> 4) << 3) + j;
        const int n = nf * 16 + (l & 15);
        wg2f[id] = f2bf((y ? Wr2 : Ws2)[(size_t)k * 128 + n]);
        return;
    }
    id -= 32768;

    if (id < 256) {     // bias2 = [bs2 | br2]
        bias2[id] = (id < 128) ? bs2[id] : br2[id - 128];
        return;
    }
    id -= 256;

    if (id < 73728) {   // wg3fT: transposed A-fragments of [Wc1a | Wc1b]
        const int p = id / 36864, r = id % 36864;
        const int frag = r >> 9, l = (r >> 3) & 63, j = r & 7;
        const int mt = frag >> 2, ks = frag & 3;
        const int k = ks * 32 + ((l >> 4) << 3) + j;     // Wc1 row (K dim)
        const int n = mt * 16 + (l & 15);                // Wc1 col (output)
        wg3fT[id] = f2bf(Wc1[(size_t)(p * 144 + k) * 288 + n]);
        return;
    }
    id -= 73728;

    if (id < 5120) {    // wc2f2: head B-frags, fp16, 2 halves x 5 ks (tail 0-pad)
        const int f = id >> 9, l = (id >> 3) & 63, j = id & 7;
        const int h = f / 5, ks = f % 5;
        const int klocal = ks * 32 + ((l >> 4) << 3) + j;
        const int c = l & 15;
        float v = 0.f;
        if (klocal < 144 && c < 5) v = Wc2[(size_t)(h * 144 + klocal) * 5 + c];
        wc2f2[id] = f2h(v);
    }
}

// ---------------------------------------------------------------------------
// Kernel A: h2 = relu( relu(spikes @ wg1 + bias1) @ diag(Ws2,Wr2) + bias2 )
// 64 rows/block, 4 waves (2 row x 2 col). h1 lives in LDS.  (R9-proven.)
// ---------------------------------------------------------------------------
#define H1S 264   // shorts per h1 LDS row

__global__ __launch_bounds__(256) void fused12(
    const float* __restrict__ spikes,
    const unsigned short* __restrict__ wg1f, const float* __restrict__ bias1,
    const unsigned short* __restrict__ wg2f, const float* __restrict__ bias2,
    unsigned short* __restrict__ h2)
{
    __shared__ unsigned short h1l[64 * H1S];     // 33,792 B
    const int row0 = blockIdx.x * 64;
    const int tid = threadIdx.x;
    const int w = tid >> 6, l = tid & 63;
    const int wm = w >> 1, wn = w & 1;
    const int lm = l & 15, lk = l >> 4;
    const int wrow = wm * 32;

    bf16x8 a0[2];
#pragma unroll
    for (int rf = 0; rf < 2; rf++) {
        bf16x8 tv = {0, 0, 0, 0, 0, 0, 0, 0};
        if (lk < 2) {
            const float* p = spikes + (size_t)(row0 + wrow + rf * 16 + lm) * 16 + lk * 8;
            const float4 v0 = *reinterpret_cast<const float4*>(p);
            const float4 v1 = *reinterpret_cast<const float4*>(p + 4);
            tv[0] = (short)f2bf(v0.x); tv[1] = (short)f2bf(v0.y);
            tv[2] = (short)f2bf(v0.z); tv[3] = (short)f2bf(v0.w);
            tv[4] = (short)f2bf(v1.x); tv[5] = (short)f2bf(v1.y);
            tv[6] = (short)f2bf(v1.z); tv[7] = (short)f2bf(v1.w);
        }
        a0[rf] = tv;
    }
    f32x4 acc[2][8];
#pragma unroll
    for (int rf = 0; rf < 2; rf++)
#pragma unroll
        for (int nf = 0; nf < 8; nf++) acc[rf][nf] = (f32x4){0.f, 0.f, 0.f, 0.f};

#pragma unroll
    for (int nf = 0; nf < 8; nf++) {
        const bf16x8 bfr = *reinterpret_cast<const bf16x8*>(
            wg1f + (size_t)(wn * 8 + nf) * 512 + l * 8);
        acc[0][nf] = __builtin_amdgcn_mfma_f32_16x16x32_bf16(a0[0], bfr, acc[0][nf], 0, 0, 0);
        acc[1][nf] = __builtin_amdgcn_mfma_f32_16x16x32_bf16(a0[1], bfr, acc[1][nf], 0, 0, 0);
    }
#pragma unroll
    for (int rf = 0; rf < 2; rf++)
#pragma unroll
        for (int nf = 0; nf < 8; nf++) {
            const int gc = wn * 128 + nf * 16 + lm;
            const float add = bias1[gc];
#pragma unroll
            for (int reg = 0; reg < 4; reg++) {
                const int r = wrow + rf * 16 + lk * 4 + reg;
                h1l[r * H1S + gc] = f2bf(fmaxf(acc[rf][nf][reg] + add, 0.f));
            }
        }
    __syncthreads();

#pragma unroll
    for (int rf = 0; rf < 2; rf++)
#pragma unroll
        for (int nf = 0; nf < 8; nf++) acc[rf][nf] = (f32x4){0.f, 0.f, 0.f, 0.f};

#pragma unroll
    for (int ks = 0; ks < 4; ks++) {
        bf16x8 a[2];
        a[0] = *reinterpret_cast<const bf16x8*>(
            &h1l[(wrow + lm) * H1S + wn * 128 + ks * 32 + lk * 8]);
        a[1] = *reinterpret_cast<const bf16x8*>(
            &h1l[(wrow + 16 + lm) * H1S + wn * 128 + ks * 32 + lk * 8]);
#pragma unroll
        for (int nf = 0; nf < 8; nf++) {
            const bf16x8 bfr = *reinterpret_cast<const bf16x8*>(
                wg2f + (size_t)wn * 16384 + (size_t)(ks * 8 + nf) * 512 + l * 8);
            acc[0][nf] = __builtin_amdgcn_mfma_f32_16x16x32_bf16(a[0], bfr, acc[0][nf], 0, 0, 0);
            acc[1][nf] = __builtin_amdgcn_mfma_f32_16x16x32_bf16(a[1], bfr, acc[1][nf], 0, 0, 0);
        }
    }
#pragma unroll
    for (int rf = 0; rf < 2; rf++)
#pragma unroll
        for (int nf = 0; nf < 8; nf++) {
            const int gc = wn * 128 + nf * 16 + lm;
            const float add = bias2[gc];
#pragma unroll
            for (int reg = 0; reg < 4; reg++) {
                const size_t r = (size_t)(row0 + wrow + rf * 16 + lk * 4 + reg);
                h2[r * 256 + gc] = f2bf(fmaxf(acc[rf][nf][reg] + add, 0.f));
            }
        }
}

// ---------------------------------------------------------------------------
// Kernel B: per (slice, k-half). grid = 510*2, 512 thr (8 waves), 76 KB LDS
// -> 2 blocks/CU co-resident.  (Math identical to R15's PASSING final6;
// the 2.6M scattered fp32 atomics are replaced by coalesced slot-ordered
// partial stores -- no RMW.)
// ---------------------------------------------------------------------------
#define SROWB2 304
#define SMATB2 38912     // 128 * 304
#define LDS_B3 77824     // 2 * SMATB2
#define PART_N 2611200   // 510*1024*5 floats per k-half

__global__ __launch_bounds__(512) void final6(
    const unsigned short* __restrict__ h2,
    const unsigned short* __restrict__ wg3fT, const float* __restrict__ Pt,
    const unsigned short* __restrict__ wc2f2, const float* __restrict__ bc2,
    const int* __restrict__ sidx, const int* __restrict__ ridx,
    float* __restrict__ part)
{
    extern __shared__ unsigned char lds[];
    const int bid = blockIdx.x;
    const int slice = bid >> 1, h = bid & 1;     // k-half: cols [h*144, h*144+144)
    const int b = slice / 255, t = slice % 255;
    const int tid = threadIdx.x, w = tid >> 6, l = tid & 63;
    const int lm = l & 15, lk = l >> 4;

    // ---- head B-frags + gather tables ----
    f16x8 bfrag[5];
#pragma unroll
    for (int ks = 0; ks < 5; ks++)
        bfrag[ks] = *reinterpret_cast<const f16x8*>(wc2f2 + (h * 5 + ks) * 512 + l * 8);
    const float bias = (lm < 5) ? bc2[lm] : 0.f;
    int srw[8], rrw[8];
#pragma unroll
    for (int j = 0; j < 8; j++) {
        const int base = (w * 8 + j) * 16 + lm;
        srw[j] = sidx[base];
        rrw[j] = ridx[base];
    }

    // ---- phase C: S (p=0) / R'+P (p=1), 9 mt tiles, transposed MFMA ----
    {
        const int p = w >> 2, rowg = w & 3;      // 2p x 4 rowg x 32 rows
        const size_t hrow0 = (size_t)((b * 256 + t + 1 - p) * 128 + rowg * 32 + lm);

        bf16x8 bfr[2][4];
#pragma unroll
        for (int half = 0; half < 2; half++)
#pragma unroll
            for (int ks = 0; ks < 4; ks++)
                bfr[half][ks] = *reinterpret_cast<const bf16x8*>(
                    h2 + (hrow0 + half * 16) * 256 + p * 128 + ks * 32 + lk * 8);

        unsigned char* mb0 = lds + p * SMATB2 + (rowg * 32 + lm) * SROWB2;
        unsigned char* mb1 = mb0 + 16 * SROWB2;

#pragma unroll
        for (int m9 = 0; m9 < 9; m9++) {
            const int mt = h * 9 + m9;
            f32x4 acc0 = {0.f, 0.f, 0.f, 0.f};
            f32x4 acc1 = {0.f, 0.f, 0.f, 0.f};
#pragma unroll
            for (int ks = 0; ks < 4; ks++) {
                const bf16x8 afr = *reinterpret_cast<const bf16x8*>(
                    wg3fT + ((size_t)(((p * 18 + mt) << 2) + ks) << 9) + l * 8);
                acc0 = __builtin_amdgcn_mfma_f32_16x16x32_bf16(afr, bfr[0][ks], acc0, 0, 0, 0);
                acc1 = __builtin_amdgcn_mfma_f32_16x16x32_bf16(afr, bfr[1][ks], acc1, 0, 0, 0);
            }
            const int c0 = mt * 16 + lk * 4;
            float4 pa = {0.f, 0.f, 0.f, 0.f};
            if (p) pa = *reinterpret_cast<const float4*>(Pt + (size_t)t * 288 + c0);
            const int boff = m9 * 32 + lk * 8;
            uint2 wv;
            wv.x = cvtpkrtz(acc0[0] + pa.x, acc0[1] + pa.y);
            wv.y = cvtpkrtz(acc0[2] + pa.z, acc0[3] + pa.w);
            *reinterpret_cast<uint2*>(mb0 + boff) = wv;
            wv.x = cvtpkrtz(acc1[0] + pa.x, acc1[1] + pa.y);
            wv.y = cvtpkrtz(acc1[2] + pa.z, acc1[3] + pa.w);
            *reinterpret_cast<uint2*>(mb1 + boff) = wv;
        }
    }
    __syncthreads();

    // ---- phase D: gather + packed relu + head partial sums (plain stores) ----
    float* pb = part + (size_t)h * PART_N + (size_t)slice * 1024 * 5;
#pragma unroll
    for (int g = 0; g < 2; g++) {
        f32x4 acc[4];
#pragma unroll
        for (int it = 0; it < 4; it++) acc[it] = (f32x4){0.f, 0.f, 0.f, 0.f};

#pragma unroll
        for (int ks = 0; ks < 5; ks++) {
            u32x4 s4[4], r4[4];
#pragma unroll
            for (int it = 0; it < 4; it++) {
                const int j = g * 4 + it;
                if (ks < 4 || lk < 2) {
                    s4[it] = *reinterpret_cast<const u32x4*>(
                        lds + srw[j] * SROWB2 + ks * 64 + lk * 16);
                    r4[it] = *reinterpret_cast<const u32x4*>(
                        lds + SMATB2 + rrw[j] * SROWB2 + ks * 64 + lk * 16);
                } else {
                    s4[it] = (u32x4){0u, 0u, 0u, 0u};
                    r4[it] = (u32x4){0u, 0u, 0u, 0u};
                }
            }
#pragma unroll
            for (int it = 0; it < 4; it++) {
                u32x4 hw;
#pragma unroll
                for (int i = 0; i < 4; i++) {
                    unsigned hsum, hrel;
                    asm("v_pk_add_f16 %0, %1, %2" : "=v"(hsum) : "v"(s4[it][i]), "v"(r4[it][i]));
                    asm("v_pk_max_f16 %0, %1, 0"  : "=v"(hrel) : "v"(hsum));
                    hw[i] = hrel;
                }
                acc[it] = __builtin_amdgcn_mfma_f32_16x16x32_f16(
                    __builtin_bit_cast(f16x8, hw), bfrag[ks], acc[it], 0, 0, 0);
            }
        }
        if (lm < 5) {
#pragma unroll
            for (int it = 0; it < 4; it++) {
                const int base = (w * 8 + g * 4 + it) * 16 + lk * 4;
#pragma unroll
                for (int reg = 0; reg < 4; reg++) {
                    const int slot = base + reg;
                    pb[(size_t)slot * 5 + lm] = acc[it][reg] + (h ? 0.f : bias);
                }
            }
        }
    }
}

// ---------------------------------------------------------------------------
// Combine: out[slice, eidx[slot], c] = part0[slice,slot,c] + part1[...]
// Reads coalesced, one scatter write. Fully deterministic.
// ---------------------------------------------------------------------------
__global__ __launch_bounds__(256) void combine_k(
    const float* __restrict__ part, const int* __restrict__ eidx,
    float* __restrict__ out)
{
    const int idx = blockIdx.x * 256 + threadIdx.x;   // slot-major, 522240
    if (idx >= 510 * 1024) return;
    const int slice = idx >> 10, slot = idx & 1023;
    const int edge = eidx[slot];
    const float* p0 = part + (size_t)idx * 5;
    const float* p1 = part + PART_N + (size_t)idx * 5;
    float* op = out + ((size_t)slice * 1024 + edge) * 5;
#pragma unroll
    for (int c = 0; c < 5; c++) op[c] = p0[c] + p1[c];
}

// ---------------------------------------------------------------------------
extern "C" void kernel_launch(void* const* d_in, const int* in_sizes, int n_in,
                              void* d_out, int out_size, void* d_ws, size_t ws_size,
                              hipStream_t stream)
{
    const float* spikes = (const float*)d_in[0];
    const float* W_emb  = (const float*)d_in[1];
    const float* b_emb  = (const float*)d_in[2];
    const float* Ws1    = (const float*)d_in[3];
    const float* bs1    = (const float*)d_in[4];
    const float* Ws2    = (const float*)d_in[5];
    const float* bs2    = (const float*)d_in[6];
    const float* Wr1    = (const float*)d_in[7];
    const float* br1    = (const float*)d_in[8];
    const float* Wr2    = (const float*)d_in[9];
    const float* br2    = (const float*)d_in[10];
    const float* Wc1    = (const float*)d_in[11];
    const float* bc1    = (const float*)d_in[12];
    const float* Wc2    = (const float*)d_in[13];
    const float* bc2    = (const float*)d_in[14];
    const int*   se     = (const int*)d_in[15];
    const int*   re     = (const int*)d_in[16];

    float* out = (float*)d_out;
    float* ws  = (float*)d_ws;

    // workspace layout (float offsets, all 16B-aligned):
    float*          P     = ws;                                   // 73,440 f
    float*          bias1 = ws + 73440;                           // 256 f
    float*          bias2 = ws + 73696;                           // 256 f
    unsigned short* wg1f  = (unsigned short*)(ws + 73952);        // 8,192 u16
    unsigned short* wg2f  = (unsigned short*)(ws + 78048);        // 32,768 u16
    unsigned short* wg3fT = (unsigned short*)(ws + 94432);        // 73,728 u16
    unsigned short* wc2f2 = (unsigned short*)(ws + 131296);       // 5,120 u16
    int*            eidx  = (int*)(ws + 133856);                  // 1,024 i32
    int*            sidx  = (int*)(ws + 134880);                  // 1,024 i32
    int*            ridx  = (int*)(ws + 135904);                  // 1,024 i32
    unsigned short* h2    = (unsigned short*)(ws + 136928);       // 16.78M u16
    float*          part  = ws + 8525536;                         // 2*2,611,200 f

    const dim3 blk(256);

    (void)hipFuncSetAttribute(reinterpret_cast<const void*>(final6),
                              hipFuncAttributeMaxDynamicSharedMemorySize, LDS_B3);

    prep_kernel<<<758, blk, 0, stream>>>(
        W_emb, b_emb, Ws1, bs1, Wr1, br1, Ws2, bs2, Wr2, br2, Wc1, bc1, Wc2,
        se, re, P, bias1, bias2, wg1f, wg2f, wg3fT, wc2f2, eidx, sidx, ridx);

    // h2 = relu(relu(spikes @ wg1 + bias1) @ diag(Ws2,Wr2) + bias2) -> HBM/L3
    fused12<<<1024, blk, 0, stream>>>(spikes, wg1f, bias1, wg2f, bias2, h2);

    // per (slice, k-half): S/R half into LDS + gather + head partials
    final6<<<1020, dim3(512), LDS_B3, stream>>>(
        h2, wg3fT, P, wc2f2, bc2, sidx, ridx, part);

    // combine partials + scatter to edge order
    combine_k<<<2040, blk, 0, stream>>>(part, eidx, out);
}

// Round 18
// 49.042 us; speedup vs baseline: 1.5386x; 1.5386x over previous
//
#include <hip/hip_runtime.h>
#include <hip/hip_bf16.h>
#include <hip/hip_fp16.h>
#include <cstdint>
#include <cstddef>

typedef __attribute__((ext_vector_type(8))) short bf16x8;
typedef __attribute__((ext_vector_type(8))) _Float16 f16x8;
typedef __attribute__((ext_vector_type(4))) float f32x4;
typedef __attribute__((ext_vector_type(4))) unsigned u32x4;

__device__ inline unsigned short f2bf(float f) {   // RNE bf16
    __hip_bfloat16 h = __float2bfloat16(f);
    return __builtin_bit_cast(unsigned short, h);
}
__device__ inline unsigned short f2h(float f) {    // RNE fp16
    _Float16 h = (_Float16)f;
    return __builtin_bit_cast(unsigned short, h);
}
__device__ inline unsigned cvtpkrtz(float lo, float hi) {  // 2xf32 -> packed fp16
    unsigned pk;
    asm("v_cvt_pkrtz_f16_f32 %0, %1, %2" : "=v"(pk) : "v"(lo), "v"(hi));
    return pk;
}

// ---------------------------------------------------------------------------
// One-shot prep.
// Blocks 0..286: P[t,h] (trig table in LDS).
// Blocks 287..754: weight fragments (id carve).
// Block 755: O(N) counting sort of edges by key se*8|(re&7); slot = rank.
//   (R13-proven: conflicts 5.8M -> 3.5M. R14 interleave and R15/R17 split-K
//   both A/B-refuted; this is the empirical optimum configuration.)
// ---------------------------------------------------------------------------
__global__ void prep_kernel(
    const float* __restrict__ W_emb, const float* __restrict__ b_emb,
    const float* __restrict__ Ws1, const float* __restrict__ bs1,
    const float* __restrict__ Wr1, const float* __restrict__ br1,
    const float* __restrict__ Ws2, const float* __restrict__ bs2,
    const float* __restrict__ Wr2, const float* __restrict__ br2,
    const float* __restrict__ Wc1, const float* __restrict__ bc1,
    const float* __restrict__ Wc2,
    const int* __restrict__ se, const int* __restrict__ re,
    float* __restrict__ P, float* __restrict__ bias1, float* __restrict__ bias2,
    unsigned short* __restrict__ wg1f, unsigned short* __restrict__ wg2f,
    unsigned short* __restrict__ wg3fT, unsigned short* __restrict__ wc2f,
    int* __restrict__ eidx, int* __restrict__ sidx, int* __restrict__ ridx)
{
    const int tid = threadIdx.x;

    if (blockIdx.x < 287) {            // ---- P section (ids 0..73439) ----
        __shared__ float sv[3][16], cv[3][16];
        const int base = blockIdx.x * 256;
        const int t0 = base / 288;
        if (tid < 48) {
            const int dt = tid >> 4, i = tid & 15;
            const int ii = i >> 1;
            const float div = expf(-1.1512925464970229f * (float)ii);
            const float ang = (float)(t0 + dt) * div;
            sv[dt][i] = sinf(ang);
            cv[dt][i] = cosf(ang);
        }
        __syncthreads();
        const int id = base + tid;
        if (id < 73440) {
            const int t = id / 288, ho = id % 288;
            const int dt = t - t0;
            float acc = bc1[ho];
#pragma unroll
            for (int i = 0; i < 8; i++) {
                acc += sv[dt + 1][2 * i] * Wc1[(size_t)(128 + 2 * i) * 288 + ho];
                acc += cv[dt + 1][2 * i] * Wc1[(size_t)(129 + 2 * i) * 288 + ho];
                acc += sv[dt][2 * i]     * Wc1[(size_t)(272 + 2 * i) * 288 + ho];
                acc += cv[dt][2 * i]     * Wc1[(size_t)(273 + 2 * i) * 288 + ho];
            }
            P[id] = acc;
        }
        return;
    }

    if (blockIdx.x == 755) {           // ---- O(N) edge counting sort ----
        __shared__ int sse[1024], sre[1024];
        __shared__ int hist[1024];
        __shared__ int scn[256];
        for (int i = tid; i < 1024; i += 256) {
            sse[i] = se[i]; sre[i] = re[i]; hist[i] = 0;
        }
        __syncthreads();
        for (int i = tid; i < 1024; i += 256)
            atomicAdd(&hist[sse[i] * 8 + (sre[i] & 7)], 1);
        __syncthreads();
        int loc[4]; int s = 0;
#pragma unroll
        for (int j = 0; j < 4; j++) { loc[j] = s; s += hist[tid * 4 + j]; }
        scn[tid] = s;
        __syncthreads();
        for (int off = 1; off < 256; off <<= 1) {
            const int v = (tid >= off) ? scn[tid - off] : 0;
            __syncthreads();
            scn[tid] += v;
            __syncthreads();
        }
        const int excl = scn[tid] - s;
#pragma unroll
        for (int j = 0; j < 4; j++) hist[tid * 4 + j] = excl + loc[j];
        __syncthreads();
        for (int i = tid; i < 1024; i += 256) {
            const int key = sse[i] * 8 + (sre[i] & 7);
            const int slot = atomicAdd(&hist[key], 1);
            eidx[slot] = i; sidx[slot] = sse[i]; ridx[slot] = sre[i];
        }
        return;
    }

    int id = (blockIdx.x - 287) * 256 + tid;

    if (id < 8192) {    // wg1f: [W_emb@Ws1 | W_emb@Wr1], K padded 16->32
        const int y = id >> 12, r = id & 4095;
        const int f = r >> 9, l = (r >> 3) & 63, j = r & 7;
        const int k = ((l >> 4) << 3) + j;          // 0..31
        const int n = f * 16 + (l & 15);
        float v = 0.f;
        if (k < 16) {
            const float* Wx = y ? Wr1 : Ws1;
            for (int d = 0; d < 128; d++) v += W_emb[k * 128 + d] * Wx[d * 128 + n];
        }
        wg1f[id] = f2bf(v);
        return;
    }
    id -= 8192;

    if (id < 256) {     // bias1 = [bs1 + b_emb@Ws1 | br1 + b_emb@Wr1]
        const int y = id >> 7, c = id & 127;
        const float* Wx = y ? Wr1 : Ws1;
        float v = (y ? br1 : bs1)[c];
        for (int d = 0; d < 128; d++) v += b_emb[d] * Wx[d * 128 + c];
        bias1[id] = v;
        return;
    }
    id -= 256;

    if (id < 32768) {   // wg2f: [Ws2 | Wr2] fragments
        const int y = id >> 14, r = id & 16383;
        const int f = r >> 9, l = (r >> 3) & 63, j = r & 7;
        const int ks = f >> 3, nf = f & 7;
        const int k = ks * 32 + ((l >> 4) << 3) + j;
        const int n = nf * 16 + (l & 15);
        wg2f[id] = f2bf((y ? Wr2 : Ws2)[(size_t)k * 128 + n]);
        return;
    }
    id -= 32768;

    if (id < 256) {     // bias2 = [bs2 | br2]
        bias2[id] = (id < 128) ? bs2[id] : br2[id - 128];
        return;
    }
    id -= 256;

    if (id < 73728) {   // wg3fT: transposed A-fragments of [Wc1a | Wc1b]
        const int p = id / 36864, r = id % 36864;
        const int frag = r >> 9, l = (r >> 3) & 63, j = r & 7;
        const int mt = frag >> 2, ks = frag & 3;
        const int k = ks * 32 + ((l >> 4) << 3) + j;     // Wc1 row (K dim)
        const int n = mt * 16 + (l & 15);                // Wc1 col (output)
        wg3fT[id] = f2bf(Wc1[(size_t)(p * 144 + k) * 288 + n]);
        return;
    }
    id -= 73728;

    if (id < 4608) {    // wc2f: head weight fragments, FP16 (288x5 padded to 16)
        const int j = id & 7, l = (id >> 3) & 63, ks = id >> 9;
        const int k = ks * 32 + ((l >> 4) << 3) + j;
        const int c = l & 15;
        wc2f[id] = (c < 5) ? f2h(Wc2[(size_t)k * 5 + c]) : (unsigned short)0;
    }
}

// ---------------------------------------------------------------------------
// Mega-fused per-(b,t)-slice kernel, 16 waves (1024 thr):
// A: h1 -> LDS (same-wave consumer: NO barrier, lgkmcnt only);
// B: h2 -> LDS; C-load: h2 B-frags -> regs; C: S^T/R'^T (fp16) -> LDS
// [p][128][592]; D: 2-deep software-pipelined gather + packed relu +
// 9 x mfma_f32_16x16x32_f16 -> out via eidx.  h2 never touches HBM.
// ---------------------------------------------------------------------------
#define H1ROWB 272       // h1/h2 LDS row stride (17*16)
#define H1YB   34816     // 128 * 272 per y-half
#define H2BASE 69632     // h2 region base (2 * H1YB)
#define SROWB  592
#define SMATB  75776     // 128 * 592
#define LDS_B2 151552    // 2 * SMATB  (phases A/B live in [0,139264))

__global__ __launch_bounds__(1024) void final5(
    const float* __restrict__ spikes,
    const unsigned short* __restrict__ wg1f, const float* __restrict__ bias1,
    const unsigned short* __restrict__ wg2f, const float* __restrict__ bias2,
    const unsigned short* __restrict__ wg3fT, const float* __restrict__ Pt,
    const unsigned short* __restrict__ wc2f, const float* __restrict__ bc2,
    const int* __restrict__ eidx, const int* __restrict__ sidx,
    const int* __restrict__ ridx, float* __restrict__ out)
{
    extern __shared__ unsigned char lds[];
    const int slice = blockIdx.x;                // 0..509
    const int b = slice / 255, t = slice % 255;
    const int tid = threadIdx.x, w = tid >> 6, l = tid & 63;
    const int lm = l & 15, lk = l >> 4;

    // ---- phase A: h1 (both chains) into LDS ----
    {
        const int y = w >> 3, rowblk = w & 7;    // y: 0=send(t+1), 1=recv(t)
        const int tt = y ? t : t + 1;
        bf16x8 a0 = {0, 0, 0, 0, 0, 0, 0, 0};
        if (lk < 2) {
            const float* p = spikes +
                ((size_t)((b * 256 + tt) * 128 + rowblk * 16 + lm)) * 16 + lk * 8;
            const float4 v0 = *reinterpret_cast<const float4*>(p);
            const float4 v1 = *reinterpret_cast<const float4*>(p + 4);
            a0[0] = (short)f2bf(v0.x); a0[1] = (short)f2bf(v0.y);
            a0[2] = (short)f2bf(v0.z); a0[3] = (short)f2bf(v0.w);
            a0[4] = (short)f2bf(v1.x); a0[5] = (short)f2bf(v1.y);
            a0[6] = (short)f2bf(v1.z); a0[7] = (short)f2bf(v1.w);
        }
        f32x4 acc[8];
#pragma unroll
        for (int nf = 0; nf < 8; nf++) acc[nf] = (f32x4){0.f, 0.f, 0.f, 0.f};
#pragma unroll
        for (int nf = 0; nf < 8; nf++) {
            const bf16x8 bfr = *reinterpret_cast<const bf16x8*>(
                wg1f + y * 4096 + nf * 512 + l * 8);
            acc[nf] = __builtin_amdgcn_mfma_f32_16x16x32_bf16(a0, bfr, acc[nf], 0, 0, 0);
        }
        unsigned char* hb = lds + y * H1YB + (rowblk * 16 + lk * 4) * H1ROWB;
#pragma unroll
        for (int nf = 0; nf < 8; nf++) {
            const int c = nf * 16 + lm;
            const float add = bias1[y * 128 + c];
#pragma unroll
            for (int reg = 0; reg < 4; reg++)
                *reinterpret_cast<unsigned short*>(hb + reg * H1ROWB + c * 2) =
                    f2bf(fmaxf(acc[nf][reg] + add, 0.f));
        }
    }
    // A->B is a same-wave dependency (wave (y,rowblk) reads exactly the h1
    // tile it wrote): wave-local LDS drain suffices, no cross-wave barrier.
    asm volatile("s_waitcnt lgkmcnt(0)" ::: "memory");

    // ---- phase B: h2 (both chains) into LDS ----
    {
        const int y = w >> 3, rowblk = w & 7;
        bf16x8 a[4];
#pragma unroll
        for (int ks = 0; ks < 4; ks++)
            a[ks] = *reinterpret_cast<const bf16x8*>(
                lds + y * H1YB + (rowblk * 16 + lm) * H1ROWB + ks * 64 + lk * 16);
        f32x4 acc[8];
#pragma unroll
        for (int nf = 0; nf < 8; nf++) acc[nf] = (f32x4){0.f, 0.f, 0.f, 0.f};
#pragma unroll
        for (int ks = 0; ks < 4; ks++)
#pragma unroll
            for (int nf = 0; nf < 8; nf++) {
                const bf16x8 bfr = *reinterpret_cast<const bf16x8*>(
                    wg2f + (size_t)y * 16384 + (size_t)(ks * 8 + nf) * 512 + l * 8);
                acc[nf] = __builtin_amdgcn_mfma_f32_16x16x32_bf16(a[ks], bfr, acc[nf], 0, 0, 0);
            }
        unsigned char* hb = lds + H2BASE + y * H1YB + (rowblk * 16 + lk * 4) * H1ROWB;
#pragma unroll
        for (int nf = 0; nf < 8; nf++) {
            const int c = nf * 16 + lm;
            const float add = bias2[y * 128 + c];
#pragma unroll
            for (int reg = 0; reg < 4; reg++)
                *reinterpret_cast<unsigned short*>(hb + reg * H1ROWB + c * 2) =
                    f2bf(fmaxf(acc[nf][reg] + add, 0.f));
        }
    }
    __syncthreads();

    // ---- phase C-load: h2 B-frags -> regs; head frags; gather row tables ----
    const int rowg = w & 3, colg = w >> 2;
    const int p  = colg >> 1;                    // 0 = S(send), 1 = R(recv)
    const int mtb = (colg & 1) * 9;
    bf16x8 bfr[2][4];
#pragma unroll
    for (int half = 0; half < 2; half++)
#pragma unroll
        for (int ks = 0; ks < 4; ks++)
            bfr[half][ks] = *reinterpret_cast<const bf16x8*>(
                lds + H2BASE + p * H1YB +
                (rowg * 32 + half * 16 + lm) * H1ROWB + ks * 64 + lk * 16);
    f16x8 bfrag[9];
#pragma unroll
    for (int ks = 0; ks < 9; ks++)
        bfrag[ks] = *reinterpret_cast<const f16x8*>(wc2f + (ks * 64 + l) * 8);
    const float bias = (lm < 5) ? bc2[lm] : 0.f;
    int srw[4], rrw[4];
#pragma unroll
    for (int it = 0; it < 4; it++) {
        const int base = (w * 4 + it) * 16 + lm;
        srw[it] = sidx[base];
        rrw[it] = ridx[base];
    }
    __syncthreads();

    // ---- phase C: S/R tiles -> LDS (fp16, overwrites h1/h2) ----
    {
        unsigned char* mb0 = lds + p * SMATB + (rowg * 32 + lm) * SROWB;
        unsigned char* mb1 = mb0 + 16 * SROWB;
#pragma unroll
        for (int m9 = 0; m9 < 9; m9++) {
            const int mt = mtb + m9;
            f32x4 acc0 = {0.f, 0.f, 0.f, 0.f};
            f32x4 acc1 = {0.f, 0.f, 0.f, 0.f};
#pragma unroll
            for (int ks = 0; ks < 4; ks++) {
                const bf16x8 afr = *reinterpret_cast<const bf16x8*>(
                    wg3fT + ((size_t)(((p * 18 + mt) << 2) + ks) << 9) + l * 8);
                acc0 = __builtin_amdgcn_mfma_f32_16x16x32_bf16(afr, bfr[0][ks], acc0, 0, 0, 0);
                acc1 = __builtin_amdgcn_mfma_f32_16x16x32_bf16(afr, bfr[1][ks], acc1, 0, 0, 0);
            }
            const int c0 = mt * 16 + lk * 4;
            float4 pa = {0.f, 0.f, 0.f, 0.f};
            if (p) pa = *reinterpret_cast<const float4*>(Pt + (size_t)t * 288 + c0);
            const int boff = mt * 32 + lk * 8;
            uint2 wv;
            wv.x = cvtpkrtz(acc0[0] + pa.x, acc0[1] + pa.y);
            wv.y = cvtpkrtz(acc0[2] + pa.z, acc0[3] + pa.w);
            *reinterpret_cast<uint2*>(mb0 + boff) = wv;
            wv.x = cvtpkrtz(acc1[0] + pa.x, acc1[1] + pa.y);
            wv.y = cvtpkrtz(acc1[2] + pa.z, acc1[3] + pa.w);
            *reinterpret_cast<uint2*>(mb1 + boff) = wv;
        }
    }
    __syncthreads();

    // ---- phase D: 2-deep pipelined gather + relu + head ----
    {
        f32x4 acc[4];
#pragma unroll
        for (int it = 0; it < 4; it++) acc[it] = (f32x4){0.f, 0.f, 0.f, 0.f};

        u32x4 sA[4], rA[4], sB[4], rB[4];

#define LDD(S4, R4, KS)                                                       \
        {                                                                     \
            _Pragma("unroll")                                                 \
            for (int it = 0; it < 4; it++) {                                  \
                S4[it] = *reinterpret_cast<const u32x4*>(                     \
                    lds + srw[it] * SROWB + lk * 16 + (KS) * 64);             \
                R4[it] = *reinterpret_cast<const u32x4*>(                     \
                    lds + SMATB + rrw[it] * SROWB + lk * 16 + (KS) * 64);     \
            }                                                                 \
        }
#define CPD(S4, R4, KS)                                                       \
        {                                                                     \
            _Pragma("unroll")                                                 \
            for (int it = 0; it < 4; it++) {                                  \
                u32x4 hw;                                                     \
                _Pragma("unroll")                                             \
                for (int i = 0; i < 4; i++) {                                 \
                    unsigned hsum, hrel;                                      \
                    asm("v_pk_add_f16 %0, %1, %2"                             \
                        : "=v"(hsum) : "v"(S4[it][i]), "v"(R4[it][i]));       \
                    asm("v_pk_max_f16 %0, %1, 0" : "=v"(hrel) : "v"(hsum));   \
                    hw[i] = hrel;                                             \
                }                                                             \
                acc[it] = __builtin_amdgcn_mfma_f32_16x16x32_f16(             \
                    __builtin_bit_cast(f16x8, hw), bfrag[KS], acc[it], 0, 0, 0); \
            }                                                                 \
        }

        LDD(sA, rA, 0);
        LDD(sB, rB, 1); CPD(sA, rA, 0);
        LDD(sA, rA, 2); CPD(sB, rB, 1);
        LDD(sB, rB, 3); CPD(sA, rA, 2);
        LDD(sA, rA, 4); CPD(sB, rB, 3);
        LDD(sB, rB, 5); CPD(sA, rA, 4);
        LDD(sA, rA, 6); CPD(sB, rB, 5);
        LDD(sB, rB, 7); CPD(sA, rA, 6);
        LDD(sA, rA, 8); CPD(sB, rB, 7);
        CPD(sA, rA, 8);
#undef LDD
#undef CPD

        if (lm < 5) {
#pragma unroll
            for (int it = 0; it < 4; it++) {
                const int base = (w * 4 + it) * 16 + lk * 4;
#pragma unroll
                for (int reg = 0; reg < 4; reg++) {
                    const int edge = eidx[base + reg];
                    out[((size_t)slice * 1024 + edge) * 5 + lm] = acc[it][reg] + bias;
                }
            }
        }
    }
}

// ---------------------------------------------------------------------------
extern "C" void kernel_launch(void* const* d_in, const int* in_sizes, int n_in,
                              void* d_out, int out_size, void* d_ws, size_t ws_size,
                              hipStream_t stream)
{
    const float* spikes = (const float*)d_in[0];
    const float* W_emb  = (const float*)d_in[1];
    const float* b_emb  = (const float*)d_in[2];
    const float* Ws1    = (const float*)d_in[3];
    const float* bs1    = (const float*)d_in[4];
    const float* Ws2    = (const float*)d_in[5];
    const float* bs2    = (const float*)d_in[6];
    const float* Wr1    = (const float*)d_in[7];
    const float* br1    = (const float*)d_in[8];
    const float* Wr2    = (const float*)d_in[9];
    const float* br2    = (const float*)d_in[10];
    const float* Wc1    = (const float*)d_in[11];
    const float* bc1    = (const float*)d_in[12];
    const float* Wc2    = (const float*)d_in[13];
    const float* bc2    = (const float*)d_in[14];
    const int*   se     = (const int*)d_in[15];
    const int*   re     = (const int*)d_in[16];

    float* out = (float*)d_out;
    float* ws  = (float*)d_ws;

    // workspace layout (float offsets, all 16B-aligned):
    float*          P     = ws;                                   // 73,440 f
    float*          bias1 = ws + 73440;                           // 256 f
    float*          bias2 = ws + 73696;                           // 256 f
    unsigned short* wg1f  = (unsigned short*)(ws + 73952);        // 8,192 u16
    unsigned short* wg2f  = (unsigned short*)(ws + 78048);        // 32,768 u16
    unsigned short* wg3fT = (unsigned short*)(ws + 94432);        // 73,728 u16
    unsigned short* wc2f  = (unsigned short*)(ws + 131296);       // 4,608 u16
    int*            eidx  = (int*)(ws + 133600);                  // 1,024 i32
    int*            sidx  = (int*)(ws + 134624);                  // 1,024 i32
    int*            ridx  = (int*)(ws + 135648);                  // 1,024 i32

    const dim3 blk(256);

    (void)hipFuncSetAttribute(reinterpret_cast<const void*>(final5),
                              hipFuncAttributeMaxDynamicSharedMemorySize, LDS_B2);

    prep_kernel<<<756, blk, 0, stream>>>(
        W_emb, b_emb, Ws1, bs1, Wr1, br1, Ws2, bs2, Wr2, br2, Wc1, bc1, Wc2,
        se, re, P, bias1, bias2, wg1f, wg2f, wg3fT, wc2f, eidx, sidx, ridx);

    // everything else fused per slice: h1 -> h2 -> S/R -> gather -> head
    final5<<<510, dim3(1024), LDS_B2, stream>>>(
        spikes, wg1f, bias1, wg2f, bias2, wg3fT, P, wc2f, bc2,
        eidx, sidx, ridx, out);
}